// Round 3
// baseline (145.890 us; speedup 1.0000x reference)
//
#include <hip/hip_runtime.h>

// Shapes fixed by the reference: B=4, N=M=384, D=256.
#define DD 256
#define NN 384
#define BB 4
#define BN (BB * NN)         // 1536
#define MSPLIT 4
#define MCHUNK (NN / MSPLIT) // 96
#define PSTRIDE (BN * DD)    // one partial plane: 393216 floats

// tanh(s) = 1 - 2/(exp2(2*log2e*s)+1). K pre-scaled by 2*log2e.
// Masked (mask=1) entries: tanh(s-1e9) = -1 exactly -> contribution is -v,
// handled by a wave-uniform branch (mask is independent of d = lane).
constexpr float TWO_LOG2E = 2.8853900817779268f;

// ---------------------------------------------------------------------------
// Projections: grid (BN/8, 3), block 256 (tid = d). NO LDS: the x-row values
// are wave-uniform -> compiler emits s_load (scalar pipe), FMA reads SGPR*VGPR.
// R2's version was LDS-issue-bound (512 ds_read_b128/wave vs 4096 cy FMA).
// ---------------------------------------------------------------------------
__global__ __launch_bounds__(256) void proj_kernel(
    const float* __restrict__ q,  const float* __restrict__ k,  const float* __restrict__ v,
    const float* __restrict__ Wq, const float* __restrict__ Wk, const float* __restrict__ Wv,
    const float* __restrict__ bq, const float* __restrict__ bk, const float* __restrict__ bv,
    float* __restrict__ Qout, float* __restrict__ KVout)
{
    const int tid  = threadIdx.x;
    const int row0 = blockIdx.x * 8;
    const int which = blockIdx.y;

    const float* X; const float* W; const float* bias; float scale; float* out; int ostride;
    if (which == 0)      { X = q; W = Wq; bias = bq; scale = 1.0f;      out = Qout;      ostride = 1; }
    else if (which == 1) { X = k; W = Wk; bias = bk; scale = TWO_LOG2E; out = KVout;     ostride = 2; }
    else                 { X = v; W = Wv; bias = bv; scale = 1.0f;      out = KVout + 1; ostride = 2; }

    const float* Xr = X + (size_t)row0 * DD;   // wave-uniform base

    float acc[8] = {0.f,0.f,0.f,0.f,0.f,0.f,0.f,0.f};
    #pragma unroll 2
    for (int k0 = 0; k0 < DD; k0 += 4) {
        float w0 = W[(k0 + 0) * DD + tid];     // coalesced vector loads
        float w1 = W[(k0 + 1) * DD + tid];
        float w2 = W[(k0 + 2) * DD + tid];
        float w3 = W[(k0 + 3) * DD + tid];
        #pragma unroll
        for (int r = 0; r < 8; ++r) {
            // wave-uniform x reads -> s_load_dwordx4, no LDS, no barrier
            acc[r] = fmaf(Xr[r * DD + k0 + 0], w0, acc[r]);
            acc[r] = fmaf(Xr[r * DD + k0 + 1], w1, acc[r]);
            acc[r] = fmaf(Xr[r * DD + k0 + 2], w2, acc[r]);
            acc[r] = fmaf(Xr[r * DD + k0 + 3], w3, acc[r]);
        }
    }
    const float bb = bias[tid];
    #pragma unroll
    for (int r = 0; r < 8; ++r)
        out[((row0 + r) * DD + tid) * ostride] = (acc[r] + bb) * scale;
}

// ---------------------------------------------------------------------------
// Fused tanh-contraction: grid (NN/4, BB, MSPLIT) = 1536 blocks (6/CU),
// block 256 (tid = d). Mask is wave-uniform -> scalar loads + s_cbranch skip:
// masked (50%) cost 2 cy (acc -= v) instead of the 22-cy exp2+rcp path.
// kv float2 load shared by the 4 rows. Partials to ws (no atomics).
// ---------------------------------------------------------------------------
__global__ __launch_bounds__(256, 6) void mhsa_kernel(
    const float* __restrict__ Q, const float* __restrict__ KV,
    const int* __restrict__ mask, float* __restrict__ outp)
{
    const int tid = threadIdx.x;         // d
    const int b   = blockIdx.y;
    const int n0  = blockIdx.x * 4;
    const int m0  = blockIdx.z * MCHUNK;

    float qv[4];
    #pragma unroll
    for (int j = 0; j < 4; ++j)
        qv[j] = Q[(b * NN + n0 + j) * DD + tid];

    // wave-uniform mask row pointers -> scalar (SMEM) loads
    const int* mrow[4];
    #pragma unroll
    for (int j = 0; j < 4; ++j)
        mrow[j] = mask + (size_t)(b * NN + n0 + j) * NN + m0;

    const float2* kvp = reinterpret_cast<const float2*>(KV)
                      + (size_t)b * NN * DD + (size_t)m0 * DD + tid;

    float acc[4] = {0.f, 0.f, 0.f, 0.f};
    for (int mg = 0; mg < MCHUNK; mg += 4) {
        float2 kv[4];
        #pragma unroll
        for (int u = 0; u < 4; ++u)
            kv[u] = kvp[(size_t)(mg + u) * DD];          // 4 L2 loads in flight
        #pragma unroll
        for (int u = 0; u < 4; ++u) {
            #pragma unroll
            for (int j = 0; j < 4; ++j) {
                if (mrow[j][mg + u]) {                   // wave-uniform s_cbranch
                    acc[j] -= kv[u].y;                   // tanh(-1e9)*v = -v exact
                } else {
                    const float x = qv[j] * kv[u].x;     // 2log2e * q*k
                    const float E = __builtin_amdgcn_exp2f(x);
                    const float r = __builtin_amdgcn_rcpf(E + 1.0f);
                    acc[j] += fmaf(-2.0f * kv[u].y, r, kv[u].y); // v*tanh
                }
            }
        }
    }
    float* po = outp + (size_t)blockIdx.z * PSTRIDE;
    #pragma unroll
    for (int j = 0; j < 4; ++j)
        po[(b * NN + n0 + j) * DD + tid] = acc[j];
}

// Sum the MSPLIT partial planes. grid BN*DD/256 = 1536 blocks.
__global__ __launch_bounds__(256) void reduce4_kernel(
    const float* __restrict__ part, float* __restrict__ out)
{
    const int i = blockIdx.x * 256 + threadIdx.x;
    out[i] = (part[i] + part[i + PSTRIDE])
           + (part[i + 2 * PSTRIDE] + part[i + 3 * PSTRIDE]);
}

extern "C" void kernel_launch(void* const* d_in, const int* in_sizes, int n_in,
                              void* d_out, int out_size, void* d_ws, size_t ws_size,
                              hipStream_t stream) {
    const float* q    = (const float*)d_in[0];
    const float* k    = (const float*)d_in[1];
    const float* v    = (const float*)d_in[2];
    const int*   mask = (const int*)  d_in[3];
    const float* Wq   = (const float*)d_in[4];
    const float* bq   = (const float*)d_in[5];
    const float* Wk   = (const float*)d_in[6];
    const float* bk   = (const float*)d_in[7];
    const float* Wv   = (const float*)d_in[8];
    const float* bv   = (const float*)d_in[9];
    float* out = (float*)d_out;

    float* Qws   = (float*)d_ws;                 // BN*DD floats      (1.57 MB)
    float* KVws  = Qws  + (size_t)BN * DD;       // BN*DD float2s     (3.15 MB)
    float* Pws   = KVws + (size_t)2 * BN * DD;   // MSPLIT*BN*DD      (6.29 MB)

    dim3 g1(BN / 8, 3);
    proj_kernel<<<g1, 256, 0, stream>>>(q, k, v, Wq, Wk, Wv, bq, bk, bv, Qws, KVws);

    dim3 g2(NN / 4, BB, MSPLIT);
    mhsa_kernel<<<g2, 256, 0, stream>>>(Qws, KVws, mask, Pws);

    reduce4_kernel<<<dim3(BN * DD / 256), 256, 0, stream>>>(Pws, out);
}